// Round 1
// baseline (14370.770 us; speedup 1.0000x reference)
//
#include <hip/hip_runtime.h>
#include <hip/hip_bf16.h>

#define DIM   1024
#define NTOK  2048
#define HEADS 16
#define DHEAD 64
#define FFH   2730
#define FF2   5460
#define DEPTH 4
#define EPS_RMS 1.1920929e-07f
#define QK_SCALE 0.125f

// ---------------- RMSNorm: one block per row, 256 threads, float4 ----------------
__global__ void rmsnorm_k(const float* __restrict__ in, const float* __restrict__ w,
                          float* __restrict__ out) {
    int row = blockIdx.x;
    int tid = threadIdx.x;
    const float4* in4 = (const float4*)(in + (size_t)row * DIM);
    float4 v = in4[tid];
    float ss = v.x * v.x + v.y * v.y + v.z * v.z + v.w * v.w;
    #pragma unroll
    for (int off = 32; off > 0; off >>= 1) ss += __shfl_down(ss, off);
    __shared__ float lds[4];
    __shared__ float stot;
    int wid = tid >> 6, lane = tid & 63;
    if (lane == 0) lds[wid] = ss;
    __syncthreads();
    if (tid == 0) stot = lds[0] + lds[1] + lds[2] + lds[3];
    __syncthreads();
    float inv = 1.0f / sqrtf(stot * (1.0f / DIM) + EPS_RMS);
    const float4* w4 = (const float4*)w;
    float4 wv = w4[tid];
    float4 o;
    o.x = v.x * inv * wv.x; o.y = v.y * inv * wv.y;
    o.z = v.z * inv * wv.z; o.w = v.w * inv * wv.w;
    ((float4*)(out + (size_t)row * DIM))[tid] = o;
}

// ---------------- Generic fp32 tiled GEMM: C[M,N] (+)= A[M,K] @ B[K,N] + bias ----
// 64x64 tile, 256 threads, 4x4 microtile, BK=16. M must be multiple of 64.
#define BM 64
#define BN 64
#define BK 16

__global__ __launch_bounds__(256) void gemm_k(
        const float* __restrict__ A, const float* __restrict__ B,
        const float* __restrict__ bias, float* __restrict__ C,
        int M, int N, int K, int addTo) {
    __shared__ __align__(16) float As[BK][68];   // [k][m], padded stride 68 (16B-aligned, conflict-lite)
    __shared__ __align__(16) float Bs[BK][BN];   // [k][n]
    int tid = threadIdx.x;
    int tx = tid & 15, ty = tid >> 4;
    int rowBase = blockIdx.y * BM;
    int colBase = blockIdx.x * BN;
    float acc[4][4] = {};
    for (int k0 = 0; k0 < K; k0 += BK) {
        #pragma unroll
        for (int i = 0; i < 4; i++) {
            int idx = tid + 256 * i;
            int r = idx >> 4, c = idx & 15;
            float val = 0.f;
            if (k0 + c < K) val = A[(size_t)(rowBase + r) * K + k0 + c];
            As[c][r] = val;
        }
        #pragma unroll
        for (int i = 0; i < 4; i++) {
            int idx = tid + 256 * i;
            int r = idx >> 6, c = idx & 63;
            float val = 0.f;
            if (k0 + r < K && colBase + c < N) val = B[(size_t)(k0 + r) * N + colBase + c];
            Bs[r][c] = val;
        }
        __syncthreads();
        #pragma unroll
        for (int kk = 0; kk < BK; kk++) {
            float4 a4 = *(const float4*)&As[kk][ty * 4];
            float4 b4 = *(const float4*)&Bs[kk][tx * 4];
            float a[4] = {a4.x, a4.y, a4.z, a4.w};
            float b[4] = {b4.x, b4.y, b4.z, b4.w};
            #pragma unroll
            for (int i = 0; i < 4; i++)
                #pragma unroll
                for (int j = 0; j < 4; j++) acc[i][j] += a[i] * b[j];
        }
        __syncthreads();
    }
    #pragma unroll
    for (int i = 0; i < 4; i++) {
        int r = rowBase + ty * 4 + i;
        #pragma unroll
        for (int j = 0; j < 4; j++) {
            int c = colBase + tx * 4 + j;
            if (c < N) {
                float v = acc[i][j];
                if (bias) v += bias[c];
                if (addTo) C[(size_t)r * N + c] += v;
                else       C[(size_t)r * N + c] = v;
            }
        }
    }
}

// ---------------- SwiGLU-fused GEMM: act = (h@Wa + ba) * gelu(h@Wg + bg) ----------
// B is w_ff_in [DIM x FF2]; a-cols = [0,FFH), g-cols = [FFH, FF2). Writes act [NTOK x FFH].
__global__ __launch_bounds__(256) void gemm_swiglu_k(
        const float* __restrict__ A, const float* __restrict__ B,
        const float* __restrict__ bias, float* __restrict__ C) {
    __shared__ __align__(16) float As[BK][68];
    __shared__ __align__(16) float Ba[BK][BN];
    __shared__ __align__(16) float Bg[BK][BN];
    int tid = threadIdx.x;
    int tx = tid & 15, ty = tid >> 4;
    int rowBase = blockIdx.y * BM;
    int colBase = blockIdx.x * BN;
    float acca[4][4] = {}, accg[4][4] = {};
    for (int k0 = 0; k0 < DIM; k0 += BK) {
        #pragma unroll
        for (int i = 0; i < 4; i++) {
            int idx = tid + 256 * i;
            int r = idx >> 4, c = idx & 15;
            As[c][r] = A[(size_t)(rowBase + r) * DIM + k0 + c];
        }
        #pragma unroll
        for (int i = 0; i < 4; i++) {
            int idx = tid + 256 * i;
            int r = idx >> 6, c = idx & 63;
            float va = 0.f, vg = 0.f;
            if (colBase + c < FFH) {
                va = B[(size_t)(k0 + r) * FF2 + colBase + c];
                vg = B[(size_t)(k0 + r) * FF2 + FFH + colBase + c];
            }
            Ba[r][c] = va;
            Bg[r][c] = vg;
        }
        __syncthreads();
        #pragma unroll
        for (int kk = 0; kk < BK; kk++) {
            float4 a4 = *(const float4*)&As[kk][ty * 4];
            float4 ba4 = *(const float4*)&Ba[kk][tx * 4];
            float4 bg4 = *(const float4*)&Bg[kk][tx * 4];
            float a[4] = {a4.x, a4.y, a4.z, a4.w};
            float bav[4] = {ba4.x, ba4.y, ba4.z, ba4.w};
            float bgv[4] = {bg4.x, bg4.y, bg4.z, bg4.w};
            #pragma unroll
            for (int i = 0; i < 4; i++)
                #pragma unroll
                for (int j = 0; j < 4; j++) {
                    acca[i][j] += a[i] * bav[j];
                    accg[i][j] += a[i] * bgv[j];
                }
        }
        __syncthreads();
    }
    #pragma unroll
    for (int i = 0; i < 4; i++) {
        int r = rowBase + ty * 4 + i;
        #pragma unroll
        for (int j = 0; j < 4; j++) {
            int c = colBase + tx * 4 + j;
            if (c < FFH) {
                float av = acca[i][j] + bias[c];
                float gv = accg[i][j] + bias[FFH + c];
                float gelu = 0.5f * gv * (1.0f + erff(gv * 0.70710678118654752f));
                C[(size_t)r * FFH + c] = av * gelu;
            }
        }
    }
}

// ---------------- mix = sigmoid(h @ w_mix + b_mix): one block per row ------------
__global__ void mix_k(const float* __restrict__ h, const float* __restrict__ wm,
                      const float* __restrict__ bm, float* __restrict__ mix) {
    int row = blockIdx.x;
    int tid = threadIdx.x;           // 256 = 16 k-lanes x 16 heads
    int hh = tid & 15, kl = tid >> 4;
    const float* hr = h + (size_t)row * DIM;
    float p = 0.f;
    for (int j = 0; j < 64; j++) {
        int k = kl + 16 * j;
        p += hr[k] * wm[k * 16 + hh];
    }
    __shared__ float lds[256];
    lds[tid] = p;
    __syncthreads();
    if (tid < 16) {
        float s = 0.f;
        #pragma unroll
        for (int k2 = 0; k2 < 16; k2++) s += lds[k2 * 16 + tid];
        s += bm[tid];
        mix[row * HEADS + tid] = 1.0f / (1.0f + expf(-s));
    }
}

// ---------------- RoPE (interleaved) on q,k + value-residual lerp, in-place ------
__global__ void rope_lerp_k(float* __restrict__ qkv, float* __restrict__ firstv,
                            const float* __restrict__ mix, int layer) {
    int row = blockIdx.x;
    int tid = threadIdx.x;
    float* qr = qkv + (size_t)row * 3072;
    #pragma unroll
    for (int it = 0; it < 2; it++) {
        int p = tid + 256 * it;       // 0..511 : 16 heads x 32 pairs
        int hh = p >> 5, pr = p & 31;
        float freq = expf(-(float)pr * (1.0f / 32.0f) * 9.2103403719762f); // 10000^(-pr/32)
        float ang = (float)row * freq;
        float s, c;
        sincosf(ang, &s, &c);
        int base = hh * 64 + pr * 2;
        float q0 = qr[base], q1 = qr[base + 1];
        qr[base]     = q0 * c - q1 * s;
        qr[base + 1] = q1 * c + q0 * s;
        float k0 = qr[1024 + base], k1 = qr[1024 + base + 1];
        qr[1024 + base]     = k0 * c - k1 * s;
        qr[1024 + base + 1] = k1 * c + k0 * s;
    }
    #pragma unroll
    for (int it = 0; it < 4; it++) {
        int d = tid + 256 * it;       // 0..1023
        float v = qr[2048 + d];
        if (layer == 0) {
            firstv[(size_t)row * DIM + d] = v;
        } else {
            int hh = d >> 6;
            float m = mix[row * HEADS + hh];
            qr[2048 + d] = v + m * (firstv[(size_t)row * DIM + d] - v);
        }
    }
}

// ---------------- block-causal flash attention -----------------------------------
// grid (16 qblocks, 16 heads), 128 threads = one query row per thread.
__global__ __launch_bounds__(128) void attn_k(const float* __restrict__ qkv,
                                              float* __restrict__ o) {
    int qb = blockIdx.x;
    int hh = blockIdx.y;
    int tid = threadIdx.x;
    int qrow = qb * 128 + tid;
    __shared__ __align__(16) float Ks[64][64];
    __shared__ __align__(16) float Vs[64][64];
    float q[64], acc[64];
    const float* qp = qkv + (size_t)qrow * 3072 + hh * 64;
    #pragma unroll
    for (int d = 0; d < 64; d++) { q[d] = qp[d] * QK_SCALE; acc[d] = 0.f; }
    float m = -3.0e38f, l = 0.f;
    int nkc = (qb + 1) * 2;   // 64-key chunks; block-causal mask is chunk-aligned
    for (int kc = 0; kc < nkc; kc++) {
        for (int idx = tid; idx < 4096; idx += 128) {
            int r = idx >> 6, c = idx & 63;
            Ks[r][c] = qkv[(size_t)(kc * 64 + r) * 3072 + 1024 + hh * 64 + c];
            Vs[r][c] = qkv[(size_t)(kc * 64 + r) * 3072 + 2048 + hh * 64 + c];
        }
        __syncthreads();
        for (int j = 0; j < 64; j++) {
            float s = 0.f;
            #pragma unroll
            for (int d = 0; d < 64; d++) s += q[d] * Ks[j][d];
            float mn = fmaxf(m, s);
            float corr = __expf(m - mn);
            float p = __expf(s - mn);
            l = l * corr + p;
            #pragma unroll
            for (int d = 0; d < 64; d++) acc[d] = acc[d] * corr + p * Vs[j][d];
            m = mn;
        }
        __syncthreads();
    }
    float invl = 1.0f / l;
    float* op = o + (size_t)qrow * DIM + hh * 64;
    #pragma unroll
    for (int d = 0; d < 64; d++) op[d] = acc[d] * invl;
}

// ---------------- driver ----------------------------------------------------------
extern "C" void kernel_launch(void* const* d_in, const int* in_sizes, int n_in,
                              void* d_out, int out_size, void* d_ws, size_t ws_size,
                              hipStream_t stream) {
    const float* tokens       = (const float*)d_in[0];
    const float* attn_norm_w  = (const float*)d_in[1];
    const float* w_qkv        = (const float*)d_in[2];
    const float* w_attn_out   = (const float*)d_in[3];
    const float* w_mix        = (const float*)d_in[4];
    const float* b_mix        = (const float*)d_in[5];
    const float* ff_norm_w    = (const float*)d_in[6];
    const float* w_ff_in      = (const float*)d_in[7];
    const float* b_ff_in      = (const float*)d_in[8];
    const float* w_ff_out     = (const float*)d_in[9];
    const float* b_ff_out     = (const float*)d_in[10];
    const float* final_norm_w = (const float*)d_in[11];

    float* ws  = (float*)d_ws;
    float* X   = ws;                                  // [2048,1024]
    float* H   = X + (size_t)NTOK * DIM;              // [2048,1024]
    float* QKV = H + (size_t)NTOK * DIM;              // [2048,3072]; reused as ACT [2048,2730]
    float* FV  = QKV + (size_t)NTOK * 3072;           // [2048,1024] first-layer v
    float* MIX = FV + (size_t)NTOK * DIM;             // [2048,16]
    float* O   = MIX + (size_t)NTOK * HEADS;          // [2048,1024]
    float* ACT = QKV;

    hipMemcpyAsync(X, tokens, (size_t)NTOK * DIM * sizeof(float),
                   hipMemcpyDeviceToDevice, stream);

    for (int i = 0; i < DEPTH; i++) {
        rmsnorm_k<<<NTOK, 256, 0, stream>>>(X, attn_norm_w + (size_t)i * DIM, H);
        gemm_k<<<dim3(3072 / BN, NTOK / BM), 256, 0, stream>>>(
            H, w_qkv + (size_t)i * DIM * 3072, nullptr, QKV, NTOK, 3072, DIM, 0);
        if (i > 0)
            mix_k<<<NTOK, 256, 0, stream>>>(H, w_mix + (size_t)i * DIM * HEADS,
                                            b_mix + (size_t)i * HEADS, MIX);
        rope_lerp_k<<<NTOK, 256, 0, stream>>>(QKV, FV, MIX, i);
        attn_k<<<dim3(16, 16), 128, 0, stream>>>(QKV, O);
        gemm_k<<<dim3(DIM / BN, NTOK / BM), 256, 0, stream>>>(
            O, w_attn_out + (size_t)i * DIM * DIM, nullptr, X, NTOK, DIM, DIM, 1);
        rmsnorm_k<<<NTOK, 256, 0, stream>>>(X, ff_norm_w + (size_t)i * DIM, H);
        gemm_swiglu_k<<<dim3((FFH + BN - 1) / BN, NTOK / BM), 256, 0, stream>>>(
            H, w_ff_in + (size_t)i * DIM * FF2, b_ff_in + (size_t)i * FF2, ACT);
        gemm_k<<<dim3(DIM / BN, NTOK / BM), 256, 0, stream>>>(
            ACT, w_ff_out + (size_t)i * FFH * DIM, b_ff_out + (size_t)i * DIM, X,
            NTOK, DIM, FFH, 1);
    }
    rmsnorm_k<<<NTOK, 256, 0, stream>>>(X, final_norm_w, (float*)d_out);
}

// Round 3
// 1359.466 us; speedup vs baseline: 10.5709x; 10.5709x over previous
//
#include <hip/hip_runtime.h>
#include <hip/hip_bf16.h>

#define DIM   1024
#define NTOK  2048
#define HEADS 16
#define FFH   2730
#define FF2   5460
#define FFHP  2752   /* FFH padded to x64 */
#define FFNP  2816   /* FFH padded to x128 */
#define DEPTH 4
#define EPS_RMS 1.1920929e-07f
#define QK_SCALE 0.125f

typedef __attribute__((ext_vector_type(8))) short bf16x8;
typedef __attribute__((ext_vector_type(4))) float f32x4;
typedef __attribute__((ext_vector_type(4))) unsigned int u32x4;

__device__ __forceinline__ unsigned short f2bf(float x) {
    unsigned u = __float_as_uint(x);
    u += 0x7fffu + ((u >> 16) & 1);          // RNE
    return (unsigned short)(u >> 16);
}
__device__ __forceinline__ unsigned pk2(float a, float b) {
    unsigned ua = __float_as_uint(a); ua += 0x7fffu + ((ua >> 16) & 1);
    unsigned ub = __float_as_uint(b); ub += 0x7fffu + ((ub >> 16) & 1);
    return (ua >> 16) | (ub & 0xffff0000u);
}

// ---------------- RMSNorm: fp32 out + optional bf16 out -------------------------
__global__ void rmsnorm_k(const float* __restrict__ in, const float* __restrict__ w,
                          float* __restrict__ out, unsigned short* __restrict__ outbf) {
    int row = blockIdx.x;
    int tid = threadIdx.x;
    const float4* in4 = (const float4*)(in + (size_t)row * DIM);
    float4 v = in4[tid];
    float ss = v.x * v.x + v.y * v.y + v.z * v.z + v.w * v.w;
    #pragma unroll
    for (int off = 32; off > 0; off >>= 1) ss += __shfl_down(ss, off);
    __shared__ float lds[4];
    __shared__ float stot;
    int wid = tid >> 6, lane = tid & 63;
    if (lane == 0) lds[wid] = ss;
    __syncthreads();
    if (tid == 0) stot = lds[0] + lds[1] + lds[2] + lds[3];
    __syncthreads();
    float inv = 1.0f / sqrtf(stot * (1.0f / DIM) + EPS_RMS);
    const float4* w4 = (const float4*)w;
    float4 wv = w4[tid];
    float4 o;
    o.x = v.x * inv * wv.x; o.y = v.y * inv * wv.y;
    o.z = v.z * inv * wv.z; o.w = v.w * inv * wv.w;
    ((float4*)(out + (size_t)row * DIM))[tid] = o;
    if (outbf) {
        unsigned long long p = (unsigned long long)pk2(o.x, o.y)
                             | ((unsigned long long)pk2(o.z, o.w) << 32);
        ((unsigned long long*)(outbf + (size_t)row * DIM))[tid] = p;
    }
}

// ---------------- weight transpose+convert: W fp32 [Ksrc][stride] -> bf16 [Np][Kp]
__global__ __launch_bounds__(256) void wconv_k(
        const float* __restrict__ W, short* __restrict__ out,
        int Ksrc, int Nsrc, int colOfs, int rowStride, int Kp, int Np) {
    __shared__ float tile[64][65];
    int k0 = blockIdx.y * 64, n0 = blockIdx.x * 64;
    int tid = threadIdx.x;
    int c = tid & 63;
    #pragma unroll
    for (int kk4 = 0; kk4 < 16; kk4++) {
        int kk = kk4 * 4 + (tid >> 6);
        int gk = k0 + kk, gn = n0 + c;
        float v = 0.f;
        if (gk < Ksrc && gn < Nsrc) v = W[(size_t)gk * rowStride + colOfs + gn];
        tile[kk][c] = v;
    }
    __syncthreads();
    #pragma unroll
    for (int it = 0; it < 4; it++) {
        int flat = tid + 256 * it;
        int nn = flat >> 4, kg = (flat & 15) * 4;
        int gn = n0 + nn, gk = k0 + kg;
        if (gn < Np && gk < Kp) {
            short4 s;
            s.x = (short)f2bf(tile[kg + 0][nn]);
            s.y = (short)f2bf(tile[kg + 1][nn]);
            s.z = (short)f2bf(tile[kg + 2][nn]);
            s.w = (short)f2bf(tile[kg + 3][nn]);
            *(short4*)(out + (size_t)gn * Kp + gk) = s;
        }
    }
}

// ---------------- generic bf16 MFMA GEMM: C[M,N](+)= A[M,Kp] @ Bt[N,Kp]^T --------
// 128x128 tile, BK=64, 4 waves (2x2), 4x4 16x16 frags/wave, XOR-swizzled LDS.
__global__ __launch_bounds__(256, 2) void gemm_bf16_k(
        const short* __restrict__ A, const short* __restrict__ Bt,
        const float* __restrict__ bias, float* __restrict__ C,
        int N, int Kp, int addTo) {
    __shared__ __align__(16) short As[128 * 64];
    __shared__ __align__(16) short Bs[128 * 64];
    int tid = threadIdx.x;
    int wv = tid >> 6, ln = tid & 63, g = ln >> 4, t = ln & 15;
    int wr = wv >> 1, wc = wv & 1;
    int rowBase = blockIdx.y * 128, colBase = blockIdx.x * 128;
    f32x4 acc[4][4] = {};
    int KT = Kp >> 6;
    for (int kt = 0; kt < KT; kt++) {
        int k0 = kt * 64;
        #pragma unroll
        for (int i = 0; i < 4; i++) {
            int idx = tid + 256 * i;
            int r = idx >> 3, kb8 = idx & 7;
            int swz = (kb8 * 16) ^ ((r & 7) << 4);
            uint4 va = *(const uint4*)(A + (size_t)(rowBase + r) * Kp + k0 + kb8 * 8);
            *(uint4*)((char*)As + r * 128 + swz) = va;
            uint4 vb = *(const uint4*)(Bt + (size_t)(colBase + r) * Kp + k0 + kb8 * 8);
            *(uint4*)((char*)Bs + r * 128 + swz) = vb;
        }
        __syncthreads();
        #pragma unroll
        for (int ks = 0; ks < 2; ks++) {
            bf16x8 af[4], bf[4];
            #pragma unroll
            for (int mi = 0; mi < 4; mi++) {
                int row = wr * 64 + mi * 16 + t;
                int kb = (ks * 64 + g * 16) ^ ((row & 7) << 4);
                af[mi] = *(const bf16x8*)((const char*)As + row * 128 + kb);
            }
            #pragma unroll
            for (int ni = 0; ni < 4; ni++) {
                int row = wc * 64 + ni * 16 + t;
                int kb = (ks * 64 + g * 16) ^ ((row & 7) << 4);
                bf[ni] = *(const bf16x8*)((const char*)Bs + row * 128 + kb);
            }
            #pragma unroll
            for (int mi = 0; mi < 4; mi++)
                #pragma unroll
                for (int ni = 0; ni < 4; ni++)
                    acc[mi][ni] = __builtin_amdgcn_mfma_f32_16x16x32_bf16(
                        af[mi], bf[ni], acc[mi][ni], 0, 0, 0);
        }
        __syncthreads();
    }
    #pragma unroll
    for (int mi = 0; mi < 4; mi++)
        #pragma unroll
        for (int ni = 0; ni < 4; ni++) {
            int col = colBase + wc * 64 + ni * 16 + t;
            float bv = bias ? bias[col] : 0.f;
            #pragma unroll
            for (int r = 0; r < 4; r++) {
                int row = rowBase + wr * 64 + mi * 16 + g * 4 + r;
                float v = acc[mi][ni][r] + bv;
                float* cp = C + (size_t)row * N + col;
                if (addTo) *cp += v; else *cp = v;
            }
        }
}

// ---------------- SwiGLU fused GEMM: act = (h@Wa+ba)*gelu(h@Wg+bg) -> bf16 -------
__global__ __launch_bounds__(256, 2) void gemm_swiglu_k(
        const short* __restrict__ A, const short* __restrict__ Ba,
        const short* __restrict__ Bg, const float* __restrict__ biasIn,
        unsigned short* __restrict__ actbf) {
    __shared__ __align__(16) short As[128 * 64];
    __shared__ __align__(16) short B1[128 * 64];
    __shared__ __align__(16) short B2[128 * 64];
    int tid = threadIdx.x;
    int wv = tid >> 6, ln = tid & 63, g = ln >> 4, t = ln & 15;
    int wr = wv >> 1, wc = wv & 1;
    int rowBase = blockIdx.y * 128, colBase = blockIdx.x * 128;
    f32x4 acca[4][4] = {};
    f32x4 accg[4][4] = {};
    for (int kt = 0; kt < 16; kt++) {
        int k0 = kt * 64;
        #pragma unroll
        for (int i = 0; i < 4; i++) {
            int idx = tid + 256 * i;
            int r = idx >> 3, kb8 = idx & 7;
            int swz = (kb8 * 16) ^ ((r & 7) << 4);
            uint4 va = *(const uint4*)(A + (size_t)(rowBase + r) * 1024 + k0 + kb8 * 8);
            *(uint4*)((char*)As + r * 128 + swz) = va;
            uint4 vb = *(const uint4*)(Ba + (size_t)(colBase + r) * 1024 + k0 + kb8 * 8);
            *(uint4*)((char*)B1 + r * 128 + swz) = vb;
            uint4 vg = *(const uint4*)(Bg + (size_t)(colBase + r) * 1024 + k0 + kb8 * 8);
            *(uint4*)((char*)B2 + r * 128 + swz) = vg;
        }
        __syncthreads();
        #pragma unroll
        for (int ks = 0; ks < 2; ks++) {
            bf16x8 af[4], b1f[4], b2f[4];
            #pragma unroll
            for (int mi = 0; mi < 4; mi++) {
                int row = wr * 64 + mi * 16 + t;
                int kb = (ks * 64 + g * 16) ^ ((row & 7) << 4);
                af[mi] = *(const bf16x8*)((const char*)As + row * 128 + kb);
            }
            #pragma unroll
            for (int ni = 0; ni < 4; ni++) {
                int row = wc * 64 + ni * 16 + t;
                int kb = (ks * 64 + g * 16) ^ ((row & 7) << 4);
                b1f[ni] = *(const bf16x8*)((const char*)B1 + row * 128 + kb);
                b2f[ni] = *(const bf16x8*)((const char*)B2 + row * 128 + kb);
            }
            #pragma unroll
            for (int mi = 0; mi < 4; mi++)
                #pragma unroll
                for (int ni = 0; ni < 4; ni++) {
                    acca[mi][ni] = __builtin_amdgcn_mfma_f32_16x16x32_bf16(
                        af[mi], b1f[ni], acca[mi][ni], 0, 0, 0);
                    accg[mi][ni] = __builtin_amdgcn_mfma_f32_16x16x32_bf16(
                        af[mi], b2f[ni], accg[mi][ni], 0, 0, 0);
                }
        }
        __syncthreads();
    }
    const float rs2 = 0.70710678118654752f;
    #pragma unroll
    for (int mi = 0; mi < 4; mi++)
        #pragma unroll
        for (int ni = 0; ni < 4; ni++) {
            int col = colBase + wc * 64 + ni * 16 + t;
            if (col < FFHP) {
                float ba = (col < FFH) ? biasIn[col] : 0.f;
                float bg = (col < FFH) ? biasIn[FFH + col] : 0.f;
                #pragma unroll
                for (int r = 0; r < 4; r++) {
                    int row = rowBase + wr * 64 + mi * 16 + g * 4 + r;
                    unsigned short outv = 0;
                    if (col < FFH) {
                        float a_ = acca[mi][ni][r] + ba;
                        float g_ = accg[mi][ni][r] + bg;
                        float gel = 0.5f * g_ * (1.0f + erff(g_ * rs2));
                        outv = f2bf(a_ * gel);
                    }
                    actbf[(size_t)row * FFHP + col] = outv;
                }
            }
        }
}

// ---------------- mix = sigmoid(h @ w_mix + b_mix) -------------------------------
__global__ void mix_k(const float* __restrict__ h, const float* __restrict__ wm,
                      const float* __restrict__ bm, float* __restrict__ mix) {
    int row = blockIdx.x;
    int tid = threadIdx.x;
    int hh = tid & 15, kl = tid >> 4;
    const float* hr = h + (size_t)row * DIM;
    float p = 0.f;
    for (int j = 0; j < 64; j++) {
        int k = kl + 16 * j;
        p += hr[k] * wm[k * 16 + hh];
    }
    __shared__ float lds[256];
    lds[tid] = p;
    __syncthreads();
    if (tid < 16) {
        float s = 0.f;
        #pragma unroll
        for (int k2 = 0; k2 < 16; k2++) s += lds[k2 * 16 + tid];
        s += bm[tid];
        mix[row * HEADS + tid] = 1.0f / (1.0f + expf(-s));
    }
}

// ---------------- RoPE (interleaved) on q,k + value-residual lerp, in-place ------
__global__ void rope_lerp_k(float* __restrict__ qkv, float* __restrict__ firstv,
                            const float* __restrict__ mix, int layer) {
    int row = blockIdx.x;
    int tid = threadIdx.x;
    float* qr = qkv + (size_t)row * 3072;
    #pragma unroll
    for (int it = 0; it < 2; it++) {
        int p = tid + 256 * it;
        int hh = p >> 5, pr = p & 31;
        float freq = expf(-(float)pr * (1.0f / 32.0f) * 9.2103403719762f);
        float ang = (float)row * freq;
        float s, c;
        sincosf(ang, &s, &c);
        int base = hh * 64 + pr * 2;
        float q0 = qr[base], q1 = qr[base + 1];
        qr[base]     = q0 * c - q1 * s;
        qr[base + 1] = q1 * c + q0 * s;
        float k0 = qr[1024 + base], k1 = qr[1024 + base + 1];
        qr[1024 + base]     = k0 * c - k1 * s;
        qr[1024 + base + 1] = k1 * c + k0 * s;
    }
    #pragma unroll
    for (int it = 0; it < 4; it++) {
        int d = tid + 256 * it;
        float v = qr[2048 + d];
        if (layer == 0) {
            firstv[(size_t)row * DIM + d] = v;
        } else {
            int hh = d >> 6;
            float m = mix[row * HEADS + hh];
            qr[2048 + d] = v + m * (firstv[(size_t)row * DIM + d] - v);
        }
    }
}

// ---------------- MFMA flash attention (block-causal, chunk-aligned mask) --------
// grid(16 qtiles,16 heads), 512 thr = 8 waves x 16 q rows each.
// Swapped QK^T: S^T = mfma(K_frag, Q_frag) puts q = lane&15 -> softmax needs only
// 2 shuffles. P is round-tripped through per-wave LDS (no barrier needed) so the
// PV A-fragment and the V^T B-fragment use the IDENTICAL k-mapping (32ks+8g+j).
__global__ __launch_bounds__(512, 2) void attn_mfma_k(const float* __restrict__ qkv,
                                                      unsigned short* __restrict__ obf) {
    const int qt = blockIdx.x, h = blockIdx.y;
    const int tid = threadIdx.x;
    const int wv = tid >> 6, ln = tid & 63, g = ln >> 4, t = ln & 15;
    __shared__ __align__(16) short Ks[64 * 64];     // [key][d], XOR-swizzled rows
    __shared__ __align__(16) short Vt[64 * 64];     // [d][key], XOR-swizzled rows
    __shared__ __align__(16) short Plds[8 * 16 * 64]; // per-wave [q][key], swizzled

    bf16x8 qf[2];
    {
        const float* qp = qkv + (size_t)(qt * 128 + wv * 16 + t) * 3072 + h * 64;
        #pragma unroll
        for (int ks = 0; ks < 2; ks++) {
            float4 u0 = *(const float4*)(qp + ks * 32 + g * 8);
            float4 u1 = *(const float4*)(qp + ks * 32 + g * 8 + 4);
            u32x4 pu;
            pu[0] = pk2(u0.x * QK_SCALE, u0.y * QK_SCALE);
            pu[1] = pk2(u0.z * QK_SCALE, u0.w * QK_SCALE);
            pu[2] = pk2(u1.x * QK_SCALE, u1.y * QK_SCALE);
            pu[3] = pk2(u1.z * QK_SCALE, u1.w * QK_SCALE);
            qf[ks] = __builtin_bit_cast(bf16x8, pu);
        }
    }
    f32x4 acc_o[4] = {};
    float mrun = -3.0e38f, lrun = 0.f;
    char* pw = (char*)(Plds + wv * 1024);
    const int nch = (qt + 1) * 2;
    for (int kc = 0; kc < nch; kc++) {
        // ---- stage K (row-major, swizzled) and V^T (transposed, swizzled) ----
        #pragma unroll
        for (int it = 0; it < 2; it++) {
            int flat = tid + 512 * it;
            int key = flat >> 4, dg = flat & 15;
            const float* sk = qkv + (size_t)(kc * 64 + key) * 3072 + 1024 + h * 64 + dg * 4;
            float4 kv = *(const float4*)sk;
            float4 vv = *(const float4*)(sk + 1024);
            int kb = (dg * 8) ^ ((key & 7) << 4);
            unsigned long long kp = (unsigned long long)pk2(kv.x, kv.y)
                                  | ((unsigned long long)pk2(kv.z, kv.w) << 32);
            *(unsigned long long*)((char*)Ks + key * 128 + kb) = kp;
            float vf[4] = {vv.x, vv.y, vv.z, vv.w};
            #pragma unroll
            for (int e = 0; e < 4; e++) {
                int d = dg * 4 + e;
                int vb = (key * 2) ^ ((d & 7) << 4);
                *(short*)((char*)Vt + d * 128 + vb) = (short)f2bf(vf[e]);
            }
        }
        __syncthreads();
        // ---- S^T = K . Q^T : lane (g,t) holds q=t, keys 16kf+4g+r ----
        f32x4 accs[4] = {};
        #pragma unroll
        for (int ks = 0; ks < 2; ks++)
            #pragma unroll
            for (int kf = 0; kf < 4; kf++) {
                int row = kf * 16 + t;
                int kb = (ks * 64 + g * 16) ^ ((row & 7) << 4);
                bf16x8 kfr = *(const bf16x8*)((const char*)Ks + row * 128 + kb);
                accs[kf] = __builtin_amdgcn_mfma_f32_16x16x32_bf16(kfr, qf[ks], accs[kf], 0, 0, 0);
            }
        // ---- online softmax over this 64-key chunk (per-lane q = t) ----
        float pm = -3.0e38f;
        #pragma unroll
        for (int kf = 0; kf < 4; kf++)
            #pragma unroll
            for (int r = 0; r < 4; r++) pm = fmaxf(pm, accs[kf][r]);
        pm = fmaxf(pm, __shfl_xor(pm, 16));
        pm = fmaxf(pm, __shfl_xor(pm, 32));
        float mnew = fmaxf(mrun, pm);
        float corr = __expf(mrun - mnew);
        mrun = mnew;
        float psum = 0.f;
        #pragma unroll
        for (int kf = 0; kf < 4; kf++)
            #pragma unroll
            for (int r = 0; r < 4; r++) {
                float pv = __expf(accs[kf][r] - mnew);
                accs[kf][r] = pv;
                psum += pv;
            }
        psum += __shfl_xor(psum, 16);
        psum += __shfl_xor(psum, 32);
        lrun = lrun * corr + psum;
        // ---- write P to per-wave LDS: Plds[q=t][key=16kf+4g+r], swizzled ----
        #pragma unroll
        for (int kf = 0; kf < 4; kf++)
            #pragma unroll
            for (int rp = 0; rp < 4; rp += 2) {
                unsigned pv = pk2(accs[kf][rp], accs[kf][rp + 1]);
                int boff = (t * 128 + (16 * kf + 4 * g + rp) * 2) ^ ((t & 7) << 4);
                *(unsigned*)(pw + boff) = pv;
            }
        // ---- rescale O accumulator (acc_o rows are q = g*4+r) ----
        float cr[4];
        #pragma unroll
        for (int r = 0; r < 4; r++) cr[r] = __shfl(corr, g * 4 + r);
        #pragma unroll
        for (int ni = 0; ni < 4; ni++)
            #pragma unroll
            for (int r = 0; r < 4; r++) acc_o[ni][r] *= cr[r];
        // ---- PV: A = P (from LDS, k-map 32ks+8g+j), B = V^T (same k-map) ----
        #pragma unroll
        for (int ks = 0; ks < 2; ks++) {
            bf16x8 pa = *(const bf16x8*)(pw + ((t * 128 + 64 * ks + 16 * g) ^ ((t & 7) << 4)));
            #pragma unroll
            for (int ni = 0; ni < 4; ni++) {
                int row = ni * 16 + t;
                int vb = (64 * ks + 16 * g) ^ ((row & 7) << 4);
                bf16x8 vbf = *(const bf16x8*)((const char*)Vt + row * 128 + vb);
                acc_o[ni] = __builtin_amdgcn_mfma_f32_16x16x32_bf16(pa, vbf, acc_o[ni], 0, 0, 0);
            }
        }
        __syncthreads();
    }
    float inv = 1.0f / lrun;
    float ir[4];
    #pragma unroll
    for (int r = 0; r < 4; r++) ir[r] = __shfl(inv, g * 4 + r);
    #pragma unroll
    for (int ni = 0; ni < 4; ni++)
        #pragma unroll
        for (int r = 0; r < 4; r++) {
            int row = qt * 128 + wv * 16 + g * 4 + r;
            int col = h * 64 + ni * 16 + t;
            obf[(size_t)row * DIM + col] = f2bf(acc_o[ni][r] * ir[r]);
        }
}

// ---------------- driver ----------------------------------------------------------
extern "C" void kernel_launch(void* const* d_in, const int* in_sizes, int n_in,
                              void* d_out, int out_size, void* d_ws, size_t ws_size,
                              hipStream_t stream) {
    const float* tokens       = (const float*)d_in[0];
    const float* attn_norm_w  = (const float*)d_in[1];
    const float* w_qkv        = (const float*)d_in[2];
    const float* w_attn_out   = (const float*)d_in[3];
    const float* w_mix        = (const float*)d_in[4];
    const float* b_mix        = (const float*)d_in[5];
    const float* ff_norm_w    = (const float*)d_in[6];
    const float* w_ff_in      = (const float*)d_in[7];
    const float* b_ff_in      = (const float*)d_in[8];
    const float* w_ff_out     = (const float*)d_in[9];
    const float* b_ff_out     = (const float*)d_in[10];
    const float* final_norm_w = (const float*)d_in[11];

    char* p = (char*)d_ws;
    auto alloc = [&](size_t bytes) {
        char* r = p;
        p += (bytes + 255) & ~(size_t)255;
        return r;
    };
    short* wq_t  = (short*)alloc(4ull * 3072 * 1024 * 2);
    short* wo_t  = (short*)alloc(4ull * 1024 * 1024 * 2);
    short* wfa_t = (short*)alloc(4ull * FFNP * 1024 * 2);
    short* wfg_t = (short*)alloc(4ull * FFNP * 1024 * 2);
    short* wfo_t = (short*)alloc(4ull * 1024 * FFHP * 2);
    float* X     = (float*)alloc((size_t)NTOK * DIM * 4);
    float* H     = (float*)alloc((size_t)NTOK * DIM * 4);
    float* QKV   = (float*)alloc((size_t)NTOK * 3072 * 4);
    float* FV    = (float*)alloc((size_t)NTOK * DIM * 4);
    float* MIX   = (float*)alloc((size_t)NTOK * HEADS * 4);
    short* Hbf   = (short*)alloc((size_t)NTOK * DIM * 2);
    short* Obf   = (short*)alloc((size_t)NTOK * DIM * 2);
    short* ACTbf = (short*)alloc((size_t)NTOK * FFHP * 2);

    // weight convert+transpose (bf16, [N][K] with zero padding)
    for (int i = 0; i < DEPTH; i++) {
        wconv_k<<<dim3(48, 16), 256, 0, stream>>>(
            w_qkv + (size_t)i * 1024 * 3072, wq_t + (size_t)i * 3072 * 1024,
            1024, 3072, 0, 3072, 1024, 3072);
        wconv_k<<<dim3(16, 16), 256, 0, stream>>>(
            w_attn_out + (size_t)i * 1024 * 1024, wo_t + (size_t)i * 1024 * 1024,
            1024, 1024, 0, 1024, 1024, 1024);
        wconv_k<<<dim3(44, 16), 256, 0, stream>>>(
            w_ff_in + (size_t)i * 1024 * FF2, wfa_t + (size_t)i * FFNP * 1024,
            1024, FFH, 0, FF2, 1024, FFNP);
        wconv_k<<<dim3(44, 16), 256, 0, stream>>>(
            w_ff_in + (size_t)i * 1024 * FF2, wfg_t + (size_t)i * FFNP * 1024,
            1024, FFH, FFH, FF2, 1024, FFNP);
        wconv_k<<<dim3(16, 43), 256, 0, stream>>>(
            w_ff_out + (size_t)i * FFH * 1024, wfo_t + (size_t)i * 1024 * FFHP,
            FFH, 1024, 0, 1024, FFHP, 1024);
    }

    hipMemcpyAsync(X, tokens, (size_t)NTOK * DIM * sizeof(float),
                   hipMemcpyDeviceToDevice, stream);

    for (int i = 0; i < DEPTH; i++) {
        rmsnorm_k<<<NTOK, 256, 0, stream>>>(X, attn_norm_w + (size_t)i * DIM, H,
                                            (unsigned short*)Hbf);
        gemm_bf16_k<<<dim3(24, 16), 256, 0, stream>>>(
            Hbf, wq_t + (size_t)i * 3072 * 1024, nullptr, QKV, 3072, 1024, 0);
        if (i > 0)
            mix_k<<<NTOK, 256, 0, stream>>>(H, w_mix + (size_t)i * DIM * HEADS,
                                            b_mix + (size_t)i * HEADS, MIX);
        rope_lerp_k<<<NTOK, 256, 0, stream>>>(QKV, FV, MIX, i);
        attn_mfma_k<<<dim3(16, 16), 512, 0, stream>>>(QKV, (unsigned short*)Obf);
        gemm_bf16_k<<<dim3(8, 16), 256, 0, stream>>>(
            Obf, wo_t + (size_t)i * 1024 * 1024, nullptr, X, 1024, 1024, 1);
        rmsnorm_k<<<NTOK, 256, 0, stream>>>(X, ff_norm_w + (size_t)i * DIM, H,
                                            (unsigned short*)Hbf);
        gemm_swiglu_k<<<dim3(22, 16), 256, 0, stream>>>(
            Hbf, wfa_t + (size_t)i * FFNP * 1024, wfg_t + (size_t)i * FFNP * 1024,
            b_ff_in + (size_t)i * FF2, (unsigned short*)ACTbf);
        gemm_bf16_k<<<dim3(8, 16), 256, 0, stream>>>(
            ACTbf, wfo_t + (size_t)i * 1024 * FFHP, b_ff_out + (size_t)i * DIM, X,
            1024, FFHP, 1);
    }
    rmsnorm_k<<<NTOK, 256, 0, stream>>>(X, final_norm_w, (float*)d_out, nullptr);
}

// Round 4
// 1325.293 us; speedup vs baseline: 10.8435x; 1.0258x over previous
//
#include <hip/hip_runtime.h>
#include <hip/hip_bf16.h>

#define DIM   1024
#define NTOK  2048
#define HEADS 16
#define FFH   2730
#define FF2   5460
#define FFHP  2752   /* FFH padded to x64 */
#define FFNP  2816   /* FFH padded to x128 */
#define DEPTH 4
#define EPS_RMS 1.1920929e-07f
#define QK_SCALE 0.125f

typedef __attribute__((ext_vector_type(8))) short bf16x8;
typedef __attribute__((ext_vector_type(4))) float f32x4;
typedef __attribute__((ext_vector_type(4))) unsigned int u32x4;

__device__ __forceinline__ unsigned short f2bf(float x) {
    unsigned u = __float_as_uint(x);
    u += 0x7fffu + ((u >> 16) & 1);          // RNE
    return (unsigned short)(u >> 16);
}
__device__ __forceinline__ unsigned pk2(float a, float b) {
    unsigned ua = __float_as_uint(a); ua += 0x7fffu + ((ua >> 16) & 1);
    unsigned ub = __float_as_uint(b); ub += 0x7fffu + ((ub >> 16) & 1);
    return (ua >> 16) | (ub & 0xffff0000u);
}

// ---------------- RMSNorm: fp32 out + optional bf16 out -------------------------
__global__ void rmsnorm_k(const float* __restrict__ in, const float* __restrict__ w,
                          float* __restrict__ out, unsigned short* __restrict__ outbf) {
    int row = blockIdx.x;
    int tid = threadIdx.x;
    const float4* in4 = (const float4*)(in + (size_t)row * DIM);
    float4 v = in4[tid];
    float ss = v.x * v.x + v.y * v.y + v.z * v.z + v.w * v.w;
    #pragma unroll
    for (int off = 32; off > 0; off >>= 1) ss += __shfl_down(ss, off);
    __shared__ float lds[4];
    __shared__ float stot;
    int wid = tid >> 6, lane = tid & 63;
    if (lane == 0) lds[wid] = ss;
    __syncthreads();
    if (tid == 0) stot = lds[0] + lds[1] + lds[2] + lds[3];
    __syncthreads();
    float inv = 1.0f / sqrtf(stot * (1.0f / DIM) + EPS_RMS);
    const float4* w4 = (const float4*)w;
    float4 wv = w4[tid];
    float4 o;
    o.x = v.x * inv * wv.x; o.y = v.y * inv * wv.y;
    o.z = v.z * inv * wv.z; o.w = v.w * inv * wv.w;
    ((float4*)(out + (size_t)row * DIM))[tid] = o;
    if (outbf) {
        unsigned long long p = (unsigned long long)pk2(o.x, o.y)
                             | ((unsigned long long)pk2(o.z, o.w) << 32);
        ((unsigned long long*)(outbf + (size_t)row * DIM))[tid] = p;
    }
}

// ---------------- weight transpose+convert: W fp32 [Ksrc][stride] -> bf16 [Np][Kp]
__global__ __launch_bounds__(256) void wconv_k(
        const float* __restrict__ W, short* __restrict__ out,
        int Ksrc, int Nsrc, int colOfs, int rowStride, int Kp, int Np) {
    __shared__ float tile[64][65];
    int k0 = blockIdx.y * 64, n0 = blockIdx.x * 64;
    int tid = threadIdx.x;
    int c = tid & 63;
    #pragma unroll
    for (int kk4 = 0; kk4 < 16; kk4++) {
        int kk = kk4 * 4 + (tid >> 6);
        int gk = k0 + kk, gn = n0 + c;
        float v = 0.f;
        if (gk < Ksrc && gn < Nsrc) v = W[(size_t)gk * rowStride + colOfs + gn];
        tile[kk][c] = v;
    }
    __syncthreads();
    #pragma unroll
    for (int it = 0; it < 4; it++) {
        int flat = tid + 256 * it;
        int nn = flat >> 4, kg = (flat & 15) * 4;
        int gn = n0 + nn, gk = k0 + kg;
        if (gn < Np && gk < Kp) {
            short4 s;
            s.x = (short)f2bf(tile[kg + 0][nn]);
            s.y = (short)f2bf(tile[kg + 1][nn]);
            s.z = (short)f2bf(tile[kg + 2][nn]);
            s.w = (short)f2bf(tile[kg + 3][nn]);
            *(short4*)(out + (size_t)gn * Kp + gk) = s;
        }
    }
}

// ---------------- bf16 MFMA GEMM, split-K: C[M,N] += A[M,Kp] @ Bt[N,Kp]^T --------
// 128x128 tile, BK=64, 4 waves (2x2), 4x4 16x16 frags/wave, XOR-swizzled LDS.
// Block z covers K-steps [z*KT/S, (z+1)*KT/S); partials atomicAdd'ed into C
// (C must be pre-initialized: residual for fused-add, zero otherwise).
template<int SPLITK>
__global__ __launch_bounds__(256, 2) void gemm_splitk_k(
        const short* __restrict__ A, const short* __restrict__ Bt,
        const float* __restrict__ bias, float* __restrict__ C,
        int N, int Kp) {
    __shared__ __align__(16) short As[128 * 64];
    __shared__ __align__(16) short Bs[128 * 64];
    int tid = threadIdx.x;
    int wv = tid >> 6, ln = tid & 63, g = ln >> 4, t = ln & 15;
    int wr = wv >> 1, wc = wv & 1;
    int rowBase = blockIdx.y * 128, colBase = blockIdx.x * 128;
    int z = blockIdx.z;
    f32x4 acc[4][4] = {};
    int KT = Kp >> 6;
    int kt0 = (KT * z) / SPLITK, kt1 = (KT * (z + 1)) / SPLITK;
    for (int kt = kt0; kt < kt1; kt++) {
        int k0 = kt * 64;
        #pragma unroll
        for (int i = 0; i < 4; i++) {
            int idx = tid + 256 * i;
            int r = idx >> 3, kb8 = idx & 7;
            int swz = (kb8 * 16) ^ ((r & 7) << 4);
            uint4 va = *(const uint4*)(A + (size_t)(rowBase + r) * Kp + k0 + kb8 * 8);
            *(uint4*)((char*)As + r * 128 + swz) = va;
            uint4 vb = *(const uint4*)(Bt + (size_t)(colBase + r) * Kp + k0 + kb8 * 8);
            *(uint4*)((char*)Bs + r * 128 + swz) = vb;
        }
        __syncthreads();
        #pragma unroll
        for (int ks = 0; ks < 2; ks++) {
            bf16x8 af[4], bf[4];
            #pragma unroll
            for (int mi = 0; mi < 4; mi++) {
                int row = wr * 64 + mi * 16 + t;
                int kb = (ks * 64 + g * 16) ^ ((row & 7) << 4);
                af[mi] = *(const bf16x8*)((const char*)As + row * 128 + kb);
            }
            #pragma unroll
            for (int ni = 0; ni < 4; ni++) {
                int row = wc * 64 + ni * 16 + t;
                int kb = (ks * 64 + g * 16) ^ ((row & 7) << 4);
                bf[ni] = *(const bf16x8*)((const char*)Bs + row * 128 + kb);
            }
            #pragma unroll
            for (int mi = 0; mi < 4; mi++)
                #pragma unroll
                for (int ni = 0; ni < 4; ni++)
                    acc[mi][ni] = __builtin_amdgcn_mfma_f32_16x16x32_bf16(
                        af[mi], bf[ni], acc[mi][ni], 0, 0, 0);
        }
        __syncthreads();
    }
    #pragma unroll
    for (int mi = 0; mi < 4; mi++)
        #pragma unroll
        for (int ni = 0; ni < 4; ni++) {
            int col = colBase + wc * 64 + ni * 16 + t;
            float bv = (bias && z == 0) ? bias[col] : 0.f;
            #pragma unroll
            for (int r = 0; r < 4; r++) {
                int row = rowBase + wr * 64 + mi * 16 + g * 4 + r;
                atomicAdd(C + (size_t)row * N + col, acc[mi][ni][r] + bv);
            }
        }
}

// ---------------- SwiGLU fused GEMM: act = (h@Wa+ba)*gelu(h@Wg+bg) -> bf16 -------
__global__ __launch_bounds__(256, 2) void gemm_swiglu_k(
        const short* __restrict__ A, const short* __restrict__ Ba,
        const short* __restrict__ Bg, const float* __restrict__ biasIn,
        unsigned short* __restrict__ actbf) {
    __shared__ __align__(16) short As[128 * 64];
    __shared__ __align__(16) short B1[128 * 64];
    __shared__ __align__(16) short B2[128 * 64];
    int tid = threadIdx.x;
    int wv = tid >> 6, ln = tid & 63, g = ln >> 4, t = ln & 15;
    int wr = wv >> 1, wc = wv & 1;
    int rowBase = blockIdx.y * 128, colBase = blockIdx.x * 128;
    f32x4 acca[4][4] = {};
    f32x4 accg[4][4] = {};
    for (int kt = 0; kt < 16; kt++) {
        int k0 = kt * 64;
        #pragma unroll
        for (int i = 0; i < 4; i++) {
            int idx = tid + 256 * i;
            int r = idx >> 3, kb8 = idx & 7;
            int swz = (kb8 * 16) ^ ((r & 7) << 4);
            uint4 va = *(const uint4*)(A + (size_t)(rowBase + r) * 1024 + k0 + kb8 * 8);
            *(uint4*)((char*)As + r * 128 + swz) = va;
            uint4 vb = *(const uint4*)(Ba + (size_t)(colBase + r) * 1024 + k0 + kb8 * 8);
            *(uint4*)((char*)B1 + r * 128 + swz) = vb;
            uint4 vg = *(const uint4*)(Bg + (size_t)(colBase + r) * 1024 + k0 + kb8 * 8);
            *(uint4*)((char*)B2 + r * 128 + swz) = vg;
        }
        __syncthreads();
        #pragma unroll
        for (int ks = 0; ks < 2; ks++) {
            bf16x8 af[4], b1f[4], b2f[4];
            #pragma unroll
            for (int mi = 0; mi < 4; mi++) {
                int row = wr * 64 + mi * 16 + t;
                int kb = (ks * 64 + g * 16) ^ ((row & 7) << 4);
                af[mi] = *(const bf16x8*)((const char*)As + row * 128 + kb);
            }
            #pragma unroll
            for (int ni = 0; ni < 4; ni++) {
                int row = wc * 64 + ni * 16 + t;
                int kb = (ks * 64 + g * 16) ^ ((row & 7) << 4);
                b1f[ni] = *(const bf16x8*)((const char*)B1 + row * 128 + kb);
                b2f[ni] = *(const bf16x8*)((const char*)B2 + row * 128 + kb);
            }
            #pragma unroll
            for (int mi = 0; mi < 4; mi++)
                #pragma unroll
                for (int ni = 0; ni < 4; ni++) {
                    acca[mi][ni] = __builtin_amdgcn_mfma_f32_16x16x32_bf16(
                        af[mi], b1f[ni], acca[mi][ni], 0, 0, 0);
                    accg[mi][ni] = __builtin_amdgcn_mfma_f32_16x16x32_bf16(
                        af[mi], b2f[ni], accg[mi][ni], 0, 0, 0);
                }
        }
        __syncthreads();
    }
    const float rs2 = 0.70710678118654752f;
    #pragma unroll
    for (int mi = 0; mi < 4; mi++)
        #pragma unroll
        for (int ni = 0; ni < 4; ni++) {
            int col = colBase + wc * 64 + ni * 16 + t;
            if (col < FFHP) {
                float ba = (col < FFH) ? biasIn[col] : 0.f;
                float bg = (col < FFH) ? biasIn[FFH + col] : 0.f;
                #pragma unroll
                for (int r = 0; r < 4; r++) {
                    int row = rowBase + wr * 64 + mi * 16 + g * 4 + r;
                    unsigned short outv = 0;
                    if (col < FFH) {
                        float a_ = acca[mi][ni][r] + ba;
                        float g_ = accg[mi][ni][r] + bg;
                        float gel = 0.5f * g_ * (1.0f + erff(g_ * rs2));
                        outv = f2bf(a_ * gel);
                    }
                    actbf[(size_t)row * FFHP + col] = outv;
                }
            }
        }
}

// ---------------- mix = sigmoid(h @ w_mix + b_mix) -------------------------------
__global__ void mix_k(const float* __restrict__ h, const float* __restrict__ wm,
                      const float* __restrict__ bm, float* __restrict__ mix) {
    int row = blockIdx.x;
    int tid = threadIdx.x;
    int hh = tid & 15, kl = tid >> 4;
    const float* hr = h + (size_t)row * DIM;
    float p = 0.f;
    for (int j = 0; j < 64; j++) {
        int k = kl + 16 * j;
        p += hr[k] * wm[k * 16 + hh];
    }
    __shared__ float lds[256];
    lds[tid] = p;
    __syncthreads();
    if (tid < 16) {
        float s = 0.f;
        #pragma unroll
        for (int k2 = 0; k2 < 16; k2++) s += lds[k2 * 16 + tid];
        s += bm[tid];
        mix[row * HEADS + tid] = 1.0f / (1.0f + expf(-s));
    }
}

// ---------------- RoPE (interleaved) on q,k + value-residual lerp, in-place ------
__global__ void rope_lerp_k(float* __restrict__ qkv, float* __restrict__ firstv,
                            const float* __restrict__ mix, int layer) {
    int row = blockIdx.x;
    int tid = threadIdx.x;
    float* qr = qkv + (size_t)row * 3072;
    #pragma unroll
    for (int it = 0; it < 2; it++) {
        int p = tid + 256 * it;
        int hh = p >> 5, pr = p & 31;
        float freq = expf(-(float)pr * (1.0f / 32.0f) * 9.2103403719762f);
        float ang = (float)row * freq;
        float s, c;
        sincosf(ang, &s, &c);
        int base = hh * 64 + pr * 2;
        float q0 = qr[base], q1 = qr[base + 1];
        qr[base]     = q0 * c - q1 * s;
        qr[base + 1] = q1 * c + q0 * s;
        float k0 = qr[1024 + base], k1 = qr[1024 + base + 1];
        qr[1024 + base]     = k0 * c - k1 * s;
        qr[1024 + base + 1] = k1 * c + k0 * s;
    }
    #pragma unroll
    for (int it = 0; it < 4; it++) {
        int d = tid + 256 * it;
        float v = qr[2048 + d];
        if (layer == 0) {
            firstv[(size_t)row * DIM + d] = v;
        } else {
            int hh = d >> 6;
            float m = mix[row * HEADS + hh];
            qr[2048 + d] = v + m * (firstv[(size_t)row * DIM + d] - v);
        }
    }
}

// ---------------- MFMA flash attention (block-causal, chunk-aligned mask) --------
// grid(16 qtiles,16 heads), 512 thr = 8 waves x 16 q rows each.
// Swapped QK^T: S^T = mfma(K_frag, Q_frag) puts q = lane&15 -> softmax needs only
// 2 shuffles. P is round-tripped through per-wave LDS (no barrier needed) so the
// PV A-fragment and the V^T B-fragment use the IDENTICAL k-mapping (32ks+8g+j).
__global__ __launch_bounds__(512, 2) void attn_mfma_k(const float* __restrict__ qkv,
                                                      unsigned short* __restrict__ obf) {
    const int qt = blockIdx.x, h = blockIdx.y;
    const int tid = threadIdx.x;
    const int wv = tid >> 6, ln = tid & 63, g = ln >> 4, t = ln & 15;
    __shared__ __align__(16) short Ks[64 * 64];     // [key][d], XOR-swizzled rows
    __shared__ __align__(16) short Vt[64 * 64];     // [d][key], XOR-swizzled rows
    __shared__ __align__(16) short Plds[8 * 16 * 64]; // per-wave [q][key], swizzled

    bf16x8 qf[2];
    {
        const float* qp = qkv + (size_t)(qt * 128 + wv * 16 + t) * 3072 + h * 64;
        #pragma unroll
        for (int ks = 0; ks < 2; ks++) {
            float4 u0 = *(const float4*)(qp + ks * 32 + g * 8);
            float4 u1 = *(const float4*)(qp + ks * 32 + g * 8 + 4);
            u32x4 pu;
            pu[0] = pk2(u0.x * QK_SCALE, u0.y * QK_SCALE);
            pu[1] = pk2(u0.z * QK_SCALE, u0.w * QK_SCALE);
            pu[2] = pk2(u1.x * QK_SCALE, u1.y * QK_SCALE);
            pu[3] = pk2(u1.z * QK_SCALE, u1.w * QK_SCALE);
            qf[ks] = __builtin_bit_cast(bf16x8, pu);
        }
    }
    f32x4 acc_o[4] = {};
    float mrun = -3.0e38f, lrun = 0.f;
    char* pw = (char*)(Plds + wv * 1024);
    const int nch = (qt + 1) * 2;
    for (int kc = 0; kc < nch; kc++) {
        // ---- stage K (row-major, swizzled) and V^T (transposed, swizzled) ----
        #pragma unroll
        for (int it = 0; it < 2; it++) {
            int flat = tid + 512 * it;
            int key = flat >> 4, dg = flat & 15;
            const float* sk = qkv + (size_t)(kc * 64 + key) * 3072 + 1024 + h * 64 + dg * 4;
            float4 kv = *(const float4*)sk;
            float4 vv = *(const float4*)(sk + 1024);
            int kb = (dg * 8) ^ ((key & 7) << 4);
            unsigned long long kp = (unsigned long long)pk2(kv.x, kv.y)
                                  | ((unsigned long long)pk2(kv.z, kv.w) << 32);
            *(unsigned long long*)((char*)Ks + key * 128 + kb) = kp;
            float vf[4] = {vv.x, vv.y, vv.z, vv.w};
            #pragma unroll
            for (int e = 0; e < 4; e++) {
                int d = dg * 4 + e;
                int vb = (key * 2) ^ ((d & 7) << 4);
                *(short*)((char*)Vt + d * 128 + vb) = (short)f2bf(vf[e]);
            }
        }
        __syncthreads();
        // ---- S^T = K . Q^T : lane (g,t) holds q=t, keys 16kf+4g+r ----
        f32x4 accs[4] = {};
        #pragma unroll
        for (int ks = 0; ks < 2; ks++)
            #pragma unroll
            for (int kf = 0; kf < 4; kf++) {
                int row = kf * 16 + t;
                int kb = (ks * 64 + g * 16) ^ ((row & 7) << 4);
                bf16x8 kfr = *(const bf16x8*)((const char*)Ks + row * 128 + kb);
                accs[kf] = __builtin_amdgcn_mfma_f32_16x16x32_bf16(kfr, qf[ks], accs[kf], 0, 0, 0);
            }
        // ---- online softmax over this 64-key chunk (per-lane q = t) ----
        float pm = -3.0e38f;
        #pragma unroll
        for (int kf = 0; kf < 4; kf++)
            #pragma unroll
            for (int r = 0; r < 4; r++) pm = fmaxf(pm, accs[kf][r]);
        pm = fmaxf(pm, __shfl_xor(pm, 16));
        pm = fmaxf(pm, __shfl_xor(pm, 32));
        float mnew = fmaxf(mrun, pm);
        float corr = __expf(mrun - mnew);
        mrun = mnew;
        float psum = 0.f;
        #pragma unroll
        for (int kf = 0; kf < 4; kf++)
            #pragma unroll
            for (int r = 0; r < 4; r++) {
                float pv = __expf(accs[kf][r] - mnew);
                accs[kf][r] = pv;
                psum += pv;
            }
        psum += __shfl_xor(psum, 16);
        psum += __shfl_xor(psum, 32);
        lrun = lrun * corr + psum;
        // ---- write P to per-wave LDS: Plds[q=t][key=16kf+4g+r], swizzled ----
        #pragma unroll
        for (int kf = 0; kf < 4; kf++)
            #pragma unroll
            for (int rp = 0; rp < 4; rp += 2) {
                unsigned pv = pk2(accs[kf][rp], accs[kf][rp + 1]);
                int boff = (t * 128 + (16 * kf + 4 * g + rp) * 2) ^ ((t & 7) << 4);
                *(unsigned*)(pw + boff) = pv;
            }
        // ---- rescale O accumulator (acc_o rows are q = g*4+r) ----
        float cr[4];
        #pragma unroll
        for (int r = 0; r < 4; r++) cr[r] = __shfl(corr, g * 4 + r);
        #pragma unroll
        for (int ni = 0; ni < 4; ni++)
            #pragma unroll
            for (int r = 0; r < 4; r++) acc_o[ni][r] *= cr[r];
        // ---- PV: A = P (from LDS, k-map 32ks+8g+j), B = V^T (same k-map) ----
        #pragma unroll
        for (int ks = 0; ks < 2; ks++) {
            bf16x8 pa = *(const bf16x8*)(pw + ((t * 128 + 64 * ks + 16 * g) ^ ((t & 7) << 4)));
            #pragma unroll
            for (int ni = 0; ni < 4; ni++) {
                int row = ni * 16 + t;
                int vb = (64 * ks + 16 * g) ^ ((row & 7) << 4);
                bf16x8 vbf = *(const bf16x8*)((const char*)Vt + row * 128 + vb);
                acc_o[ni] = __builtin_amdgcn_mfma_f32_16x16x32_bf16(pa, vbf, acc_o[ni], 0, 0, 0);
            }
        }
        __syncthreads();
    }
    float inv = 1.0f / lrun;
    float ir[4];
    #pragma unroll
    for (int r = 0; r < 4; r++) ir[r] = __shfl(inv, g * 4 + r);
    #pragma unroll
    for (int ni = 0; ni < 4; ni++)
        #pragma unroll
        for (int r = 0; r < 4; r++) {
            int row = qt * 128 + wv * 16 + g * 4 + r;
            int col = h * 64 + ni * 16 + t;
            obf[(size_t)row * DIM + col] = f2bf(acc_o[ni][r] * ir[r]);
        }
}

// ---------------- driver ----------------------------------------------------------
extern "C" void kernel_launch(void* const* d_in, const int* in_sizes, int n_in,
                              void* d_out, int out_size, void* d_ws, size_t ws_size,
                              hipStream_t stream) {
    const float* tokens       = (const float*)d_in[0];
    const float* attn_norm_w  = (const float*)d_in[1];
    const float* w_qkv        = (const float*)d_in[2];
    const float* w_attn_out   = (const float*)d_in[3];
    const float* w_mix        = (const float*)d_in[4];
    const float* b_mix        = (const float*)d_in[5];
    const float* ff_norm_w    = (const float*)d_in[6];
    const float* w_ff_in      = (const float*)d_in[7];
    const float* b_ff_in      = (const float*)d_in[8];
    const float* w_ff_out     = (const float*)d_in[9];
    const float* b_ff_out     = (const float*)d_in[10];
    const float* final_norm_w = (const float*)d_in[11];

    char* p = (char*)d_ws;
    auto alloc = [&](size_t bytes) {
        char* r = p;
        p += (bytes + 255) & ~(size_t)255;
        return r;
    };
    short* wq_t  = (short*)alloc(4ull * 3072 * 1024 * 2);
    short* wo_t  = (short*)alloc(4ull * 1024 * 1024 * 2);
    short* wfa_t = (short*)alloc(4ull * FFNP * 1024 * 2);
    short* wfg_t = (short*)alloc(4ull * FFNP * 1024 * 2);
    short* wfo_t = (short*)alloc(4ull * 1024 * FFHP * 2);
    float* X     = (float*)alloc((size_t)NTOK * DIM * 4);
    float* H     = (float*)alloc((size_t)NTOK * DIM * 4);
    float* QKV   = (float*)alloc((size_t)NTOK * 3072 * 4);
    float* FV    = (float*)alloc((size_t)NTOK * DIM * 4);
    float* MIX   = (float*)alloc((size_t)NTOK * HEADS * 4);
    short* Hbf   = (short*)alloc((size_t)NTOK * DIM * 2);
    short* Obf   = (short*)alloc((size_t)NTOK * DIM * 2);
    short* ACTbf = (short*)alloc((size_t)NTOK * FFHP * 2);

    // weight convert+transpose (bf16, [N][K] with zero padding)
    for (int i = 0; i < DEPTH; i++) {
        wconv_k<<<dim3(48, 16), 256, 0, stream>>>(
            w_qkv + (size_t)i * 1024 * 3072, wq_t + (size_t)i * 3072 * 1024,
            1024, 3072, 0, 3072, 1024, 3072);
        wconv_k<<<dim3(16, 16), 256, 0, stream>>>(
            w_attn_out + (size_t)i * 1024 * 1024, wo_t + (size_t)i * 1024 * 1024,
            1024, 1024, 0, 1024, 1024, 1024);
        wconv_k<<<dim3(44, 16), 256, 0, stream>>>(
            w_ff_in + (size_t)i * 1024 * FF2, wfa_t + (size_t)i * FFNP * 1024,
            1024, FFH, 0, FF2, 1024, FFNP);
        wconv_k<<<dim3(44, 16), 256, 0, stream>>>(
            w_ff_in + (size_t)i * 1024 * FF2, wfg_t + (size_t)i * FFNP * 1024,
            1024, FFH, FFH, FF2, 1024, FFNP);
        wconv_k<<<dim3(16, 43), 256, 0, stream>>>(
            w_ff_out + (size_t)i * FFH * 1024, wfo_t + (size_t)i * 1024 * FFHP,
            FFH, 1024, 0, 1024, FFHP, 1024);
    }

    hipMemcpyAsync(X, tokens, (size_t)NTOK * DIM * sizeof(float),
                   hipMemcpyDeviceToDevice, stream);

    for (int i = 0; i < DEPTH; i++) {
        rmsnorm_k<<<NTOK, 256, 0, stream>>>(X, attn_norm_w + (size_t)i * DIM, H,
                                            (unsigned short*)Hbf);
        hipMemsetAsync(QKV, 0, (size_t)NTOK * 3072 * sizeof(float), stream);
        gemm_splitk_k<2><<<dim3(24, 16, 2), 256, 0, stream>>>(
            Hbf, wq_t + (size_t)i * 3072 * 1024, nullptr, QKV, 3072, 1024);
        if (i > 0)
            mix_k<<<NTOK, 256, 0, stream>>>(H, w_mix + (size_t)i * DIM * HEADS,
                                            b_mix + (size_t)i * HEADS, MIX);
        rope_lerp_k<<<NTOK, 256, 0, stream>>>(QKV, FV, MIX, i);
        attn_mfma_k<<<dim3(16, 16), 512, 0, stream>>>(QKV, (unsigned short*)Obf);
        gemm_splitk_k<4><<<dim3(8, 16, 4), 256, 0, stream>>>(
            Obf, wo_t + (size_t)i * 1024 * 1024, nullptr, X, 1024, 1024);
        rmsnorm_k<<<NTOK, 256, 0, stream>>>(X, ff_norm_w + (size_t)i * DIM, H,
                                            (unsigned short*)Hbf);
        gemm_swiglu_k<<<dim3(22, 16), 256, 0, stream>>>(
            Hbf, wfa_t + (size_t)i * FFNP * 1024, wfg_t + (size_t)i * FFNP * 1024,
            b_ff_in + (size_t)i * FF2, (unsigned short*)ACTbf);
        gemm_splitk_k<4><<<dim3(8, 16, 4), 256, 0, stream>>>(
            ACTbf, wfo_t + (size_t)i * 1024 * FFHP, b_ff_out + (size_t)i * DIM, X,
            1024, FFHP);
    }
    rmsnorm_k<<<NTOK, 256, 0, stream>>>(X, final_norm_w, (float*)d_out, nullptr);
}